// Round 2
// baseline (1781.036 us; speedup 1.0000x reference)
//
#include <hip/hip_runtime.h>
#include <hip/hip_bf16.h>
#include <math.h>

#define N_NODES 40000
#define N_EDGES 320000
#define T_ITERS 3

typedef __attribute__((ext_vector_type(8))) short short8;
typedef __attribute__((ext_vector_type(4))) short short4v;
typedef __attribute__((ext_vector_type(4))) float f32x4;

static __device__ __forceinline__ short f2bf(float f) {
    union { float f; unsigned u; } x; x.f = f;
    unsigned r = (x.u + 0x7fffu + ((x.u >> 16) & 1u)) >> 16;
    return (short)r;
}
static __device__ __forceinline__ float bf2f(short s) {
    union { unsigned u; float f; } x; x.u = ((unsigned)(unsigned short)s) << 16;
    return x.f;
}

// ---------------------------------------------------------------------------
// MFMA GEMM: C[M,NC] = act(A[M,K] @ W[NC,K]^T + bias + res), bf16 out.
// Block 256 thr = 4 waves; tile 64(M) x 32*NI(N); BK=32.
// EPI=1: fused LayerNorm over rows (requires NC==128, gridDim.y==1).
// ABF16: A is bf16 (else fp32, converted while staging). row_idx gathers A rows.
// ---------------------------------------------------------------------------
template<int NI, int ACT, int EPI, bool ABF16>
__global__ __launch_bounds__(256) void gemm_bf16(
    const void* __restrict__ Aptr, const short* __restrict__ W,
    const float* __restrict__ bias, const short* __restrict__ res,
    short* __restrict__ Cb, const int* __restrict__ row_idx,
    const float* __restrict__ ln_g, const float* __restrict__ ln_b,
    int M, int K, int NC)
{
    constexpr int NT = 32 * NI;
    constexpr int STAGE = 64 * 40 * 2 + NT * 40 * 2;
    constexpr int LNB = EPI ? 64 * 132 * 4 : 0;
    constexpr int SMEM = STAGE > LNB ? STAGE : LNB;
    __shared__ __align__(16) char smem[SMEM];
    short* As = (short*)smem;
    short* Ws = (short*)(smem + 64 * 40 * 2);

    const int tid  = threadIdx.x;
    const int lane = tid & 63, wid = tid >> 6;
    const int wm = wid & 1, wn = wid >> 1;
    const int t16 = lane & 15, quad = lane >> 4;
    const long blockM = (long)blockIdx.x * 64;
    const int colBase = blockIdx.y * NT;

    f32x4 acc[2][NI];
    for (int i = 0; i < 2; i++)
        for (int j = 0; j < NI; j++)
            acc[i][j] = (f32x4){0.f, 0.f, 0.f, 0.f};

    for (int k0 = 0; k0 < K; k0 += 32) {
        if (ABF16) {
            const int r = tid >> 2, c = (tid & 3) * 8;
            long gr = blockM + r;
            long sr = (gr < M) ? (row_idx ? (long)row_idx[gr] : gr) : 0;
            *(short8*)&As[r * 40 + c] =
                *(const short8*)((const short*)Aptr + sr * K + k0 + c);
        } else {
            for (int gg = 0; gg < 2; gg++) {
                const int r = (tid >> 3) + gg * 32, c = (tid & 7) * 4;
                long gr = blockM + r;
                long sr = (gr < M) ? (row_idx ? (long)row_idx[gr] : gr) : 0;
                const float4 v = *(const float4*)((const float*)Aptr + sr * K + k0 + c);
                short4v sv;
                sv.x = f2bf(v.x); sv.y = f2bf(v.y); sv.z = f2bf(v.z); sv.w = f2bf(v.w);
                *(short4v*)&As[r * 40 + c] = sv;
            }
        }
        for (int gg = 0; gg < NI / 2; gg++) {
            const int chunk = tid + gg * 256;
            const int r = chunk >> 2, c = (chunk & 3) * 8;
            *(short8*)&Ws[r * 40 + c] =
                *(const short8*)(W + (long)(colBase + r) * K + k0 + c);
        }
        __syncthreads();
        short8 a0 = *(const short8*)&As[(wm * 32 + t16) * 40 + quad * 8];
        short8 a1 = *(const short8*)&As[(wm * 32 + 16 + t16) * 40 + quad * 8];
        for (int ni = 0; ni < NI; ni++) {
            short8 bf = *(const short8*)&Ws[(wn * 16 * NI + ni * 16 + t16) * 40 + quad * 8];
            acc[0][ni] = __builtin_amdgcn_mfma_f32_16x16x32_bf16(a0, bf, acc[0][ni], 0, 0, 0);
            acc[1][ni] = __builtin_amdgcn_mfma_f32_16x16x32_bf16(a1, bf, acc[1][ni], 0, 0, 0);
        }
        __syncthreads();
    }

    if (EPI == 0) {
        for (int mi = 0; mi < 2; mi++)
            for (int ni = 0; ni < NI; ni++) {
                const int gc = colBase + wn * 16 * NI + ni * 16 + t16;
                for (int r = 0; r < 4; r++) {
                    long gr = blockM + wm * 32 + mi * 16 + quad * 4 + r;
                    if (gr < M) {
                        float v = acc[mi][ni][r];
                        if (bias) v += bias[gc];
                        if (res)  v += bf2f(res[gr * (long)NC + gc]);
                        if (ACT == 1) v = 0.5f * v * (1.0f + erff(v * 0.70710678118654752f));
                        Cb[gr * (long)NC + gc] = f2bf(v);
                    }
                }
            }
    } else {
        // fused LayerNorm epilogue: NC==128, one block covers full rows
        float* lnb = (float*)smem;
        for (int mi = 0; mi < 2; mi++)
            for (int ni = 0; ni < NI; ni++) {
                const int bc = wn * 16 * NI + ni * 16 + t16;
                for (int r = 0; r < 4; r++) {
                    const int rl = wm * 32 + mi * 16 + quad * 4 + r;
                    long gr = blockM + rl;
                    float v = acc[mi][ni][r];
                    if (bias) v += bias[bc];
                    if (res && gr < M) v += bf2f(res[gr * 128 + bc]);
                    lnb[rl * 132 + bc] = v;
                }
            }
        __syncthreads();
        for (int j = 0; j < 16; j++) {
            const int rl = wid * 16 + j;
            long gr = blockM + rl;
            float x0 = lnb[rl * 132 + lane * 2];
            float x1 = lnb[rl * 132 + lane * 2 + 1];
            float s = x0 + x1;
            for (int o = 1; o < 64; o <<= 1) s += __shfl_xor(s, o);
            float u = s * (1.0f / 128.0f);
            float d0 = x0 - u, d1 = x1 - u;
            float vs = d0 * d0 + d1 * d1;
            for (int o = 1; o < 64; o <<= 1) vs += __shfl_xor(vs, o);
            float rstd = rsqrtf(vs * (1.0f / 128.0f) + 1e-12f);
            if (gr < M) {
                float g0 = ln_g[lane * 2], g1 = ln_g[lane * 2 + 1];
                float b0 = ln_b[lane * 2], b1 = ln_b[lane * 2 + 1];
                unsigned o01 = (unsigned)(unsigned short)f2bf(g0 * d0 * rstd + b0) |
                               ((unsigned)(unsigned short)f2bf(g1 * d1 * rstd + b1) << 16);
                *(unsigned*)&Cb[gr * 128 + lane * 2] = o01;
            }
        }
    }
}

// ---------------------------------------------------------------------------
// CSR build
// ---------------------------------------------------------------------------
__global__ void count_kernel(const int* __restrict__ dst, int* __restrict__ cnt) {
    int e = blockIdx.x * 256 + threadIdx.x;
    if (e < N_EDGES) atomicAdd(&cnt[dst[e]], 1);
}

__global__ __launch_bounds__(1024) void scan_kernel(const int* __restrict__ cnt,
                                                    int* __restrict__ rowptr) {
    __shared__ int lds[1024];
    const int tid = threadIdx.x;
    const int CH = 40;
    const int base = tid * CH;
    int sum = 0;
    for (int j = 0; j < CH; j++) { int i = base + j; if (i < N_NODES) sum += cnt[i]; }
    lds[tid] = sum;
    __syncthreads();
    for (int off = 1; off < 1024; off <<= 1) {
        int v = (tid >= off) ? lds[tid - off] : 0;
        __syncthreads();
        lds[tid] += v;
        __syncthreads();
    }
    int run = lds[tid] - sum;
    for (int j = 0; j < CH; j++) {
        int i = base + j;
        if (i < N_NODES) { rowptr[i] = run; run += cnt[i]; }
    }
    if (tid == 1023) rowptr[N_NODES] = lds[1023];
}

__global__ void fill_kernel(const int* __restrict__ src, const int* __restrict__ dst,
                            const int* __restrict__ rowptr, int* __restrict__ wo,
                            int* __restrict__ perm, int* __restrict__ srcp) {
    int e = blockIdx.x * 256 + threadIdx.x;
    if (e < N_EDGES) {
        int d = dst[e];
        int pos = atomicAdd(&wo[d], 1);
        int slot = rowptr[d] + pos;
        perm[slot] = e;
        srcp[slot] = src[e];
    }
}

// ---------------------------------------------------------------------------
// Edge attention, single-pass (no max-subtraction; alphas are O(1)).
// One wave per dst node; 4 edges in flight (16 lanes/edge, 8 dims/lane).
// QKVb bf16 [N,384]; EKV bf16 [E,256] CSR-ordered = [K(128)|V(128)] w/ bias.
// ---------------------------------------------------------------------------
__global__ __launch_bounds__(256) void edge_attn_kernel(
    const short* __restrict__ QKVb, const short* __restrict__ EKV,
    const int* __restrict__ rowptr, const int* __restrict__ srcp,
    short* __restrict__ outb)
{
    const int wid = threadIdx.x >> 6, lane = threadIdx.x & 63;
    const int n = blockIdx.x * 4 + wid;
    if (n >= N_NODES) return;
    const int g = lane >> 4, l16 = lane & 15;
    const float scale = 0.17677669529663687f;  // 1/sqrt(32)

    short8 qv = *(const short8*)&QKVb[(long)n * 384 + l16 * 8];
    float qf[8];
#pragma unroll
    for (int j = 0; j < 8; j++) qf[j] = bf2f(qv[j]);

    const int beg = rowptr[n], end = rowptr[n + 1];
    float acc[8] = {0.f, 0.f, 0.f, 0.f, 0.f, 0.f, 0.f, 0.f};
    float ssum = 0.f;

    for (int i0 = beg; i0 < end; i0 += 4) {
        const int i = i0 + g;
        const bool valid = i < end;
        const int ii = valid ? i : beg;
        const int s = srcp[ii];
        short8 kv = *(const short8*)&EKV[(long)ii * 256 + l16 * 8];
        short8 vv = *(const short8*)&EKV[(long)ii * 256 + 128 + l16 * 8];
        short8 xk = *(const short8*)&QKVb[(long)s * 384 + 128 + l16 * 8];
        short8 xv = *(const short8*)&QKVb[(long)s * 384 + 256 + l16 * 8];
        float dot = 0.f;
#pragma unroll
        for (int j = 0; j < 8; j++) dot += qf[j] * (bf2f(kv[j]) + bf2f(xk[j]));
        dot += __shfl_xor(dot, 1);
        dot += __shfl_xor(dot, 2);
        float e = valid ? __expf(dot * scale) : 0.f;
        ssum += e;
#pragma unroll
        for (int j = 0; j < 8; j++) acc[j] += e * (bf2f(vv[j]) + bf2f(xv[j]));
    }
    // combine the 4 edge-groups (same dims / same head mapping across groups)
#pragma unroll
    for (int j = 0; j < 8; j++) {
        acc[j] += __shfl_xor(acc[j], 16);
        acc[j] += __shfl_xor(acc[j], 32);
    }
    ssum += __shfl_xor(ssum, 16);
    ssum += __shfl_xor(ssum, 32);

    if (lane < 16) {
        float inv = 1.0f / (ssum + 1e-16f);
        short8 o;
#pragma unroll
        for (int j = 0; j < 8; j++) o[j] = f2bf(acc[j] * inv);
        *(short8*)&outb[(long)n * 128 + l16 * 8] = o;
    }
}

// ---------------------------------------------------------------------------
// GRU gates + hidden update + LN3, one wave per row (all bf16 in)
// ---------------------------------------------------------------------------
template<bool FINAL>
__global__ __launch_bounds__(256) void gru_ln_kernel(
    const short* __restrict__ gi, const short* __restrict__ gh,
    const short* __restrict__ hin, const float* __restrict__ g,
    const float* __restrict__ b, short* __restrict__ hout, void* __restrict__ xout)
{
    const int wid = threadIdx.x >> 6, lane = threadIdx.x & 63;
    const long n = (long)blockIdx.x * 4 + wid;
    if (n >= N_NODES) return;
    const long gb = n * 384 + lane * 2;
    const long hb = n * 128 + lane * 2;
    unsigned uir = *(const unsigned*)&gi[gb];
    unsigned uiz = *(const unsigned*)&gi[gb + 128];
    unsigned uin = *(const unsigned*)&gi[gb + 256];
    unsigned uhr = *(const unsigned*)&gh[gb];
    unsigned uhz = *(const unsigned*)&gh[gb + 128];
    unsigned uhn = *(const unsigned*)&gh[gb + 256];
    unsigned uhp = *(const unsigned*)&hin[hb];
    float ir0 = bf2f((short)uir), ir1 = bf2f((short)(uir >> 16));
    float iz0 = bf2f((short)uiz), iz1 = bf2f((short)(uiz >> 16));
    float in0 = bf2f((short)uin), in1 = bf2f((short)(uin >> 16));
    float hr0 = bf2f((short)uhr), hr1 = bf2f((short)(uhr >> 16));
    float hz0 = bf2f((short)uhz), hz1 = bf2f((short)(uhz >> 16));
    float hn0 = bf2f((short)uhn), hn1 = bf2f((short)(uhn >> 16));
    float hp0 = bf2f((short)uhp), hp1 = bf2f((short)(uhp >> 16));
    float r0 = 1.f / (1.f + __expf(-(ir0 + hr0)));
    float r1 = 1.f / (1.f + __expf(-(ir1 + hr1)));
    float z0 = 1.f / (1.f + __expf(-(iz0 + hz0)));
    float z1 = 1.f / (1.f + __expf(-(iz1 + hz1)));
    float n0 = tanhf(in0 + r0 * hn0);
    float n1 = tanhf(in1 + r1 * hn1);
    float h0 = (1.f - z0) * n0 + z0 * hp0;
    float h1 = (1.f - z1) * n1 + z1 * hp1;
    float s = h0 + h1;
    for (int o = 1; o < 64; o <<= 1) s += __shfl_xor(s, o);
    float u = s * (1.0f / 128.0f);
    float d0 = h0 - u, d1 = h1 - u;
    float vs = d0 * d0 + d1 * d1;
    for (int o = 1; o < 64; o <<= 1) vs += __shfl_xor(vs, o);
    float rstd = rsqrtf(vs * (1.0f / 128.0f) + 1e-12f);
    float g0 = g[lane * 2], g1 = g[lane * 2 + 1];
    float b0 = b[lane * 2], b1 = b[lane * 2 + 1];
    unsigned ho = (unsigned)(unsigned short)f2bf(h0) |
                  ((unsigned)(unsigned short)f2bf(h1) << 16);
    *(unsigned*)&hout[hb] = ho;
    float y0 = g0 * d0 * rstd + b0, y1 = g1 * d1 * rstd + b1;
    if (FINAL) {
        float2 o2; o2.x = y0; o2.y = y1;
        *(float2*)&((float*)xout)[hb] = o2;
    } else {
        unsigned xo = (unsigned)(unsigned short)f2bf(y0) |
                      ((unsigned)(unsigned short)f2bf(y1) << 16);
        *(unsigned*)&((short*)xout)[hb] = xo;
    }
}

// ---------------------------------------------------------------------------
// Helpers
// ---------------------------------------------------------------------------
__global__ void cvt_kernel(const float* __restrict__ s, short* __restrict__ d, int n) {
    int i = (blockIdx.x * 256 + threadIdx.x) * 4;
    if (i < n) {
        float4 v = *(const float4*)(s + i);
        short4v sv;
        sv.x = f2bf(v.x); sv.y = f2bf(v.y); sv.z = f2bf(v.z); sv.w = f2bf(v.w);
        *(short4v*)(d + i) = sv;
    }
}
__global__ void bias_cat_kernel(const float* __restrict__ bq, const float* __restrict__ bk,
                                const float* __restrict__ bv, float* __restrict__ bqkv,
                                float* __restrict__ bkv) {
    int i = blockIdx.x * 256 + threadIdx.x;
    if (i < 384) bqkv[i] = (i < 128) ? bq[i] : 0.0f;
    if (i < 256) bkv[i] = (i < 128) ? bk[i] : bv[i - 128];
}

// ---------------------------------------------------------------------------
extern "C" void kernel_launch(void* const* d_in, const int* in_sizes, int n_in,
                              void* d_out, int out_size, void* d_ws, size_t ws_size,
                              hipStream_t stream) {
    const float* x_in  = (const float*)d_in[0];
    const int*   eidx  = (const int*)d_in[1];
    const float* ea    = (const float*)d_in[2];
    const float* wq    = (const float*)d_in[3];
    const float* bq    = (const float*)d_in[4];
    const float* wk    = (const float*)d_in[5];
    const float* bk    = (const float*)d_in[6];
    const float* wv    = (const float*)d_in[7];
    const float* bv    = (const float*)d_in[8];
    const float* w_ao  = (const float*)d_in[9];
    const float* b_ao  = (const float*)d_in[10];
    const float* ln1_g = (const float*)d_in[11];
    const float* ln1_b = (const float*)d_in[12];
    const float* w_int = (const float*)d_in[13];
    const float* b_int = (const float*)d_in[14];
    const float* w_out = (const float*)d_in[15];
    const float* b_out = (const float*)d_in[16];
    const float* ln2_g = (const float*)d_in[17];
    const float* ln2_b = (const float*)d_in[18];
    const float* w_ih  = (const float*)d_in[19];
    const float* w_hh  = (const float*)d_in[20];
    const float* b_ih  = (const float*)d_in[21];
    const float* b_hh  = (const float*)d_in[22];
    const float* ln3_g = (const float*)d_in[23];
    const float* ln3_b = (const float*)d_in[24];
    const int* srcv = eidx;
    const int* dstv = eidx + N_EDGES;

    char* ws = (char*)d_ws;
    size_t off = 0;
    auto alloc = [&](size_t bytes) -> void* {
        void* p = ws + off;
        off += (bytes + 255) & ~(size_t)255;
        return p;
    };
    short* EKV  = (short*)alloc((size_t)N_EDGES * 256 * 2);
    short* Wcat = (short*)alloc(384 * 128 * 2);   // [wq;wk;wv]
    short* Wao  = (short*)alloc(128 * 128 * 2);
    short* Wint = (short*)alloc(512 * 128 * 2);
    short* Wout = (short*)alloc(128 * 512 * 2);
    short* Wih  = (short*)alloc(384 * 128 * 2);
    short* Whh  = (short*)alloc(384 * 128 * 2);
    float* bqkv = (float*)alloc(384 * 4);
    float* bkv  = (float*)alloc(256 * 4);
    int* cnt    = (int*)alloc((size_t)N_NODES * 4);
    int* wo     = (int*)alloc((size_t)N_NODES * 4);
    int* rowptr = (int*)alloc((size_t)(N_NODES + 1) * 4);
    int* perm   = (int*)alloc((size_t)N_EDGES * 4);
    int* srcp   = (int*)alloc((size_t)N_EDGES * 4);
    short* xb     = (short*)alloc((size_t)N_NODES * 128 * 2);  // x0 = h0 (bf16)
    short* QKVb   = (short*)alloc((size_t)N_NODES * 384 * 2);
    short* attraw = (short*)alloc((size_t)N_NODES * 128 * 2);  // also holds m after LN2
    short* att    = (short*)alloc((size_t)N_NODES * 128 * 2);
    short* inter  = (short*)alloc((size_t)N_NODES * 512 * 2);
    short* gi     = (short*)alloc((size_t)N_NODES * 384 * 2);
    short* gh     = (short*)alloc((size_t)N_NODES * 384 * 2);
    short* hbuf   = (short*)alloc((size_t)N_NODES * 128 * 2);
    short* xbuf   = (short*)alloc((size_t)N_NODES * 128 * 2);
    if (off > ws_size) return;

    // --- weight/bias conversion ---
    cvt_kernel<<<16, 256, 0, stream>>>(wq, Wcat, 16384);
    cvt_kernel<<<16, 256, 0, stream>>>(wk, Wcat + 16384, 16384);
    cvt_kernel<<<16, 256, 0, stream>>>(wv, Wcat + 32768, 16384);
    cvt_kernel<<<16, 256, 0, stream>>>(w_ao, Wao, 16384);
    cvt_kernel<<<64, 256, 0, stream>>>(w_int, Wint, 65536);
    cvt_kernel<<<64, 256, 0, stream>>>(w_out, Wout, 65536);
    cvt_kernel<<<48, 256, 0, stream>>>(w_ih, Wih, 49152);
    cvt_kernel<<<48, 256, 0, stream>>>(w_hh, Whh, 49152);
    cvt_kernel<<<5000, 256, 0, stream>>>(x_in, xb, N_NODES * 128);
    bias_cat_kernel<<<2, 256, 0, stream>>>(bq, bk, bv, bqkv, bkv);

    // --- CSR by dst ---
    hipMemsetAsync(cnt, 0, (size_t)N_NODES * 4, stream);
    hipMemsetAsync(wo, 0, (size_t)N_NODES * 4, stream);
    count_kernel<<<1250, 256, 0, stream>>>(dstv, cnt);
    scan_kernel<<<1, 1024, 0, stream>>>(cnt, rowptr);
    fill_kernel<<<1250, 256, 0, stream>>>(srcv, dstv, rowptr, wo, perm, srcp);

    // --- EKV = ea@[wk;wv]^T + [bk;bv], CSR-permuted, bf16 [E,256] ---
    gemm_bf16<8, 0, 0, false><<<dim3(5000, 1), 256, 0, stream>>>(
        ea, Wcat + 128 * 128, bkv, nullptr, EKV, perm, nullptr, nullptr,
        N_EDGES, 128, 256);

    const short* xcur = xb;
    const short* hcur = xb;
    for (int t = 0; t < T_ITERS; t++) {
        // QKVb = x @ [wq;wk;wv]^T + [bq;0;0]
        gemm_bf16<12, 0, 0, true><<<dim3(625, 1), 256, 0, stream>>>(
            xcur, Wcat, bqkv, nullptr, QKVb, nullptr, nullptr, nullptr,
            N_NODES, 128, 384);
        // GAT attention
        edge_attn_kernel<<<10000, 256, 0, stream>>>(QKVb, EKV, rowptr, srcp, attraw);
        // att = LN1(attraw @ w_ao^T + b_ao + x)
        gemm_bf16<4, 0, 1, true><<<dim3(625, 1), 256, 0, stream>>>(
            attraw, Wao, b_ao, xcur, att, nullptr, ln1_g, ln1_b,
            N_NODES, 128, 128);
        // inter = gelu(att @ w_int^T + b_int)
        gemm_bf16<8, 1, 0, true><<<dim3(625, 2), 256, 0, stream>>>(
            att, Wint, b_int, nullptr, inter, nullptr, nullptr, nullptr,
            N_NODES, 128, 512);
        // m = LN2(inter @ w_out^T + b_out + att)   (m -> attraw buffer)
        gemm_bf16<4, 0, 1, true><<<dim3(625, 1), 256, 0, stream>>>(
            inter, Wout, b_out, att, attraw, nullptr, ln2_g, ln2_b,
            N_NODES, 512, 128);
        // gi = m @ w_ih^T + b_ih ; gh = h @ w_hh^T + b_hh
        gemm_bf16<12, 0, 0, true><<<dim3(625, 1), 256, 0, stream>>>(
            attraw, Wih, b_ih, nullptr, gi, nullptr, nullptr, nullptr,
            N_NODES, 128, 384);
        gemm_bf16<12, 0, 0, true><<<dim3(625, 1), 256, 0, stream>>>(
            hcur, Whh, b_hh, nullptr, gh, nullptr, nullptr, nullptr,
            N_NODES, 128, 384);
        // GRU + LN3
        if (t == T_ITERS - 1)
            gru_ln_kernel<true><<<10000, 256, 0, stream>>>(
                gi, gh, hcur, ln3_g, ln3_b, hbuf, d_out);
        else
            gru_ln_kernel<false><<<10000, 256, 0, stream>>>(
                gi, gh, hcur, ln3_g, ln3_b, hbuf, xbuf);
        xcur = xbuf;
        hcur = hbuf;
    }
}

// Round 3
// 1441.594 us; speedup vs baseline: 1.2355x; 1.2355x over previous
//
#include <hip/hip_runtime.h>
#include <hip/hip_bf16.h>
#include <math.h>

#define N_NODES 40000
#define N_EDGES 320000
#define T_ITERS 3

typedef __attribute__((ext_vector_type(8))) short short8;
typedef __attribute__((ext_vector_type(4))) short short4v;
typedef __attribute__((ext_vector_type(4))) float f32x4;

static __device__ __forceinline__ short f2bf(float f) {
    union { float f; unsigned u; } x; x.f = f;
    unsigned r = (x.u + 0x7fffu + ((x.u >> 16) & 1u)) >> 16;
    return (short)r;
}
static __device__ __forceinline__ float bf2f(short s) {
    union { unsigned u; float f; } x; x.u = ((unsigned)(unsigned short)s) << 16;
    return x.f;
}

// ---------------------------------------------------------------------------
// Generic MFMA GEMM (bf16 A): C[M,NC] = A[M,K] @ W[NC,K]^T + bias (+res),
// EPI=1 fuses LayerNorm (NC==128). Tile 64 x 32*NI.
// Used for: QKV (NI=12), Wao+LN1 (NI=4).
// ---------------------------------------------------------------------------
template<int NI, int EPI>
__global__ __launch_bounds__(256) void gemm_bf16(
    const short* __restrict__ A, const short* __restrict__ W,
    const float* __restrict__ bias, const short* __restrict__ res,
    short* __restrict__ Cb,
    const float* __restrict__ ln_g, const float* __restrict__ ln_b,
    int M, int K, int NC)
{
    constexpr int NT = 32 * NI;
    constexpr int STAGE = 64 * 40 * 2 + NT * 40 * 2;
    constexpr int LNB = EPI ? 64 * 132 * 4 : 0;
    constexpr int SMEM = STAGE > LNB ? STAGE : LNB;
    __shared__ __align__(16) char smem[SMEM];
    short* As = (short*)smem;
    short* Ws = (short*)(smem + 64 * 40 * 2);

    const int tid  = threadIdx.x;
    const int lane = tid & 63, wid = tid >> 6;
    const int wm = wid & 1, wn = wid >> 1;
    const int t16 = lane & 15, quad = lane >> 4;
    const long blockM = (long)blockIdx.x * 64;
    const int colBase = blockIdx.y * NT;

    f32x4 acc[2][NI];
    for (int i = 0; i < 2; i++)
        for (int j = 0; j < NI; j++)
            acc[i][j] = (f32x4){0.f, 0.f, 0.f, 0.f};

    for (int k0 = 0; k0 < K; k0 += 32) {
        {
            const int r = tid >> 2, c = (tid & 3) * 8;
            long gr = blockM + r;
            long sr = (gr < M) ? gr : 0;
            *(short8*)&As[r * 40 + c] = *(const short8*)(A + sr * K + k0 + c);
        }
        for (int gg = 0; gg < NI / 2; gg++) {
            const int chunk = tid + gg * 256;
            const int r = chunk >> 2, c = (chunk & 3) * 8;
            *(short8*)&Ws[r * 40 + c] =
                *(const short8*)(W + (long)(colBase + r) * K + k0 + c);
        }
        __syncthreads();
        short8 a0 = *(const short8*)&As[(wm * 32 + t16) * 40 + quad * 8];
        short8 a1 = *(const short8*)&As[(wm * 32 + 16 + t16) * 40 + quad * 8];
        for (int ni = 0; ni < NI; ni++) {
            short8 bf = *(const short8*)&Ws[(wn * 16 * NI + ni * 16 + t16) * 40 + quad * 8];
            acc[0][ni] = __builtin_amdgcn_mfma_f32_16x16x32_bf16(a0, bf, acc[0][ni], 0, 0, 0);
            acc[1][ni] = __builtin_amdgcn_mfma_f32_16x16x32_bf16(a1, bf, acc[1][ni], 0, 0, 0);
        }
        __syncthreads();
    }

    if (EPI == 0) {
        for (int mi = 0; mi < 2; mi++)
            for (int ni = 0; ni < NI; ni++) {
                const int gc = colBase + wn * 16 * NI + ni * 16 + t16;
                for (int r = 0; r < 4; r++) {
                    long gr = blockM + wm * 32 + mi * 16 + quad * 4 + r;
                    if (gr < M) {
                        float v = acc[mi][ni][r];
                        if (bias) v += bias[gc];
                        Cb[gr * (long)NC + gc] = f2bf(v);
                    }
                }
            }
    } else {
        float* lnb = (float*)smem;
        for (int mi = 0; mi < 2; mi++)
            for (int ni = 0; ni < NI; ni++) {
                const int bc = wn * 16 * NI + ni * 16 + t16;
                for (int r = 0; r < 4; r++) {
                    const int rl = wm * 32 + mi * 16 + quad * 4 + r;
                    long gr = blockM + rl;
                    float v = acc[mi][ni][r];
                    if (bias) v += bias[bc];
                    if (res && gr < M) v += bf2f(res[gr * 128 + bc]);
                    lnb[rl * 132 + bc] = v;
                }
            }
        __syncthreads();
        for (int j = 0; j < 16; j++) {
            const int rl = wid * 16 + j;
            long gr = blockM + rl;
            float x0 = lnb[rl * 132 + lane * 2];
            float x1 = lnb[rl * 132 + lane * 2 + 1];
            float s = x0 + x1;
            for (int o = 1; o < 64; o <<= 1) s += __shfl_xor(s, o);
            float u = s * (1.0f / 128.0f);
            float d0 = x0 - u, d1 = x1 - u;
            float vs = d0 * d0 + d1 * d1;
            for (int o = 1; o < 64; o <<= 1) vs += __shfl_xor(vs, o);
            float rstd = rsqrtf(vs * (1.0f / 128.0f) + 1e-12f);
            if (gr < M) {
                float g0 = ln_g[lane * 2], g1 = ln_g[lane * 2 + 1];
                float b0 = ln_b[lane * 2], b1 = ln_b[lane * 2 + 1];
                unsigned o01 = (unsigned)(unsigned short)f2bf(g0 * d0 * rstd + b0) |
                               ((unsigned)(unsigned short)f2bf(g1 * d1 * rstd + b1) << 16);
                *(unsigned*)&Cb[gr * 128 + lane * 2] = o01;
            }
        }
    }
}

// ---------------------------------------------------------------------------
// EKV GEMM: EKV[eslot[e]] = ea[e] @ [wk;wv]^T + [bk;bv]  (bf16 [E,256])
// Sequential A reads (fp32 edge order), scattered 512B row writes via LDS
// transpose. Block: 64 edges; wave w -> cols w*64..+64 (4m x 4n tiles).
// ---------------------------------------------------------------------------
__global__ __launch_bounds__(256) void ekv_kernel(
    const float* __restrict__ ea, const short* __restrict__ Wkv,
    const float* __restrict__ bkv, const int* __restrict__ eslot,
    short* __restrict__ EKV)
{
    __shared__ __align__(16) char smem[64 * 272 * 2];   // Cs (epilogue)
    short* As = (short*)smem;                           // 64x40
    short* Ws = (short*)(smem + 64 * 40 * 2);           // 256x40
    short* Cs = (short*)smem;                           // 64x272

    const int tid  = threadIdx.x;
    const int lane = tid & 63, wid = tid >> 6;
    const int t16 = lane & 15, quad = lane >> 4;
    const long blockM = (long)blockIdx.x * 64;

    f32x4 acc[4][4];
    for (int i = 0; i < 4; i++)
        for (int j = 0; j < 4; j++)
            acc[i][j] = (f32x4){0.f, 0.f, 0.f, 0.f};

    for (int k0 = 0; k0 < 128; k0 += 32) {
        for (int g = 0; g < 2; g++) {
            const int r = (tid >> 3) + g * 32, c = (tid & 7) * 4;
            const float4 v = *(const float4*)(ea + (blockM + r) * 128 + k0 + c);
            short4v sv;
            sv.x = f2bf(v.x); sv.y = f2bf(v.y); sv.z = f2bf(v.z); sv.w = f2bf(v.w);
            *(short4v*)&As[r * 40 + c] = sv;
        }
        for (int g = 0; g < 4; g++) {
            const int idx = tid + g * 256;
            const int r = idx >> 2, c = (idx & 3) * 8;
            *(short8*)&Ws[r * 40 + c] = *(const short8*)(Wkv + (long)r * 128 + k0 + c);
        }
        __syncthreads();
        short8 a[4];
        for (int mi = 0; mi < 4; mi++)
            a[mi] = *(const short8*)&As[(mi * 16 + t16) * 40 + quad * 8];
        for (int ni = 0; ni < 4; ni++) {
            short8 bf = *(const short8*)&Ws[(wid * 64 + ni * 16 + t16) * 40 + quad * 8];
            for (int mi = 0; mi < 4; mi++)
                acc[mi][ni] = __builtin_amdgcn_mfma_f32_16x16x32_bf16(a[mi], bf, acc[mi][ni], 0, 0, 0);
        }
        __syncthreads();
    }

    // C-tile -> LDS (bank-safe stride 272 shorts)
    for (int mi = 0; mi < 4; mi++)
        for (int ni = 0; ni < 4; ni++) {
            const int col = wid * 64 + ni * 16 + t16;
            const float bv_ = bkv[col];
            for (int r = 0; r < 4; r++) {
                const int row = mi * 16 + quad * 4 + r;
                Cs[row * 272 + col] = f2bf(acc[mi][ni][r] + bv_);
            }
        }
    __syncthreads();
    // coalesced scattered row writes: 2048 chunks of 16B
    for (int it = 0; it < 8; it++) {
        const int idx = it * 256 + tid;
        const int row = idx >> 5, c8 = idx & 31;
        const long slot = (long)eslot[blockM + row];
        *(short8*)(EKV + slot * 256 + c8 * 8) = *(const short8*)&Cs[row * 272 + c8 * 8];
    }
}

// ---------------------------------------------------------------------------
// Fused FFN: m = LN2( gelu(att@Wint^T+b_int) @ Wout^T + b_out + att )
// Block: 128 rows, 4 waves (wave = 32 rows x 128 cols), inter kept in LDS.
// ---------------------------------------------------------------------------
__global__ __launch_bounds__(256) void ffn_kernel(
    const short* __restrict__ att, const short* __restrict__ Wint,
    const short* __restrict__ Wout, const float* __restrict__ b_int,
    const float* __restrict__ b_out, const float* __restrict__ ln_g,
    const float* __restrict__ ln_b, short* __restrict__ Mout)
{
    __shared__ __align__(16) short As[128 * 136];
    __shared__ __align__(16) short Is[128 * 136];
    __shared__ __align__(16) short Ws[128 * 40];

    const int tid  = threadIdx.x;
    const int lane = tid & 63, wid = tid >> 6;
    const int t16 = lane & 15, quad = lane >> 4;
    const long blockM = (long)blockIdx.x * 128;

    // load A tile 128x128 (also the residual)
    {
        const int r = tid >> 1, c = (tid & 1) * 64;
        long gr = blockM + r;
        long sr = (gr < N_NODES) ? gr : 0;
        const short* src = att + sr * 128 + c;
        for (int j = 0; j < 8; j++)
            *(short8*)&As[r * 136 + c + j * 8] = *(const short8*)(src + j * 8);
    }

    f32x4 acc2[2][8];
    for (int i = 0; i < 2; i++)
        for (int j = 0; j < 8; j++)
            acc2[i][j] = (f32x4){0.f, 0.f, 0.f, 0.f};
    __syncthreads();

    for (int kc = 0; kc < 4; kc++) {
        f32x4 acc1[2][8];
        for (int i = 0; i < 2; i++)
            for (int j = 0; j < 8; j++)
                acc1[i][j] = (f32x4){0.f, 0.f, 0.f, 0.f};
        // phase 1: inter_chunk = A @ Wint[kc*128..+128]^T
        for (int k0 = 0; k0 < 128; k0 += 32) {
            const int r = tid >> 1, c = (tid & 1) * 16;
            *(short8*)&Ws[r * 40 + c] =
                *(const short8*)(Wint + (long)(kc * 128 + r) * 128 + k0 + c);
            *(short8*)&Ws[r * 40 + c + 8] =
                *(const short8*)(Wint + (long)(kc * 128 + r) * 128 + k0 + c + 8);
            __syncthreads();
            short8 a[2];
            for (int mi = 0; mi < 2; mi++)
                a[mi] = *(const short8*)&As[(wid * 32 + mi * 16 + t16) * 136 + k0 + quad * 8];
            for (int ni = 0; ni < 8; ni++) {
                short8 bf = *(const short8*)&Ws[(ni * 16 + t16) * 40 + quad * 8];
                for (int mi = 0; mi < 2; mi++)
                    acc1[mi][ni] = __builtin_amdgcn_mfma_f32_16x16x32_bf16(a[mi], bf, acc1[mi][ni], 0, 0, 0);
            }
            __syncthreads();
        }
        // GELU -> Is
        for (int mi = 0; mi < 2; mi++)
            for (int ni = 0; ni < 8; ni++) {
                const int col = ni * 16 + t16;
                const float bi = b_int[kc * 128 + col];
                for (int r = 0; r < 4; r++) {
                    const int row = wid * 32 + mi * 16 + quad * 4 + r;
                    float v = acc1[mi][ni][r] + bi;
                    v = 0.5f * v * (1.0f + erff(v * 0.70710678118654752f));
                    Is[row * 136 + col] = f2bf(v);
                }
            }
        __syncthreads();
        // phase 2: acc2 += inter_chunk @ Wout[:, kc*128..+128]^T
        for (int k0 = 0; k0 < 128; k0 += 32) {
            const int r = tid >> 1, c = (tid & 1) * 16;
            *(short8*)&Ws[r * 40 + c] =
                *(const short8*)(Wout + (long)r * 512 + kc * 128 + k0 + c);
            *(short8*)&Ws[r * 40 + c + 8] =
                *(const short8*)(Wout + (long)r * 512 + kc * 128 + k0 + c + 8);
            __syncthreads();
            short8 a[2];
            for (int mi = 0; mi < 2; mi++)
                a[mi] = *(const short8*)&Is[(wid * 32 + mi * 16 + t16) * 136 + k0 + quad * 8];
            for (int ni = 0; ni < 8; ni++) {
                short8 bf = *(const short8*)&Ws[(ni * 16 + t16) * 40 + quad * 8];
                for (int mi = 0; mi < 2; mi++)
                    acc2[mi][ni] = __builtin_amdgcn_mfma_f32_16x16x32_bf16(a[mi], bf, acc2[mi][ni], 0, 0, 0);
            }
            __syncthreads();
        }
    }

    // epilogue: + b_out + residual, LN2, store
    for (int mi = 0; mi < 2; mi++) {
        float vals[8][4];
        for (int r = 0; r < 4; r++) {
            float s = 0.f;
            for (int ni = 0; ni < 8; ni++) {
                const int col = ni * 16 + t16;
                const int row = wid * 32 + mi * 16 + quad * 4 + r;
                float v = acc2[mi][ni][r] + b_out[col] + bf2f(As[row * 136 + col]);
                vals[ni][r] = v;
                s += v;
            }
            for (int o = 1; o < 16; o <<= 1) s += __shfl_xor(s, o);
            float u = s * (1.0f / 128.0f);
            float vs = 0.f;
            for (int ni = 0; ni < 8; ni++) {
                float d = vals[ni][r] - u;
                vals[ni][r] = d;
                vs += d * d;
            }
            for (int o = 1; o < 16; o <<= 1) vs += __shfl_xor(vs, o);
            float rstd = rsqrtf(vs * (1.0f / 128.0f) + 1e-12f);
            const int row = wid * 32 + mi * 16 + quad * 4 + r;
            long gr = blockM + row;
            if (gr < N_NODES)
                for (int ni = 0; ni < 8; ni++) {
                    const int col = ni * 16 + t16;
                    Mout[gr * 128 + col] = f2bf(ln_g[col] * vals[ni][r] * rstd + ln_b[col]);
                }
        }
    }
}

// ---------------------------------------------------------------------------
// Fused GRU: one GEMM  [m|h](N,256) @ Wg(512,256)^T -> {ir+hr, iz+hz, in, hn}
// + gates + h' + LN3.  Block 64 rows; wave w -> cols w*128 (4m x 8n tiles).
// ---------------------------------------------------------------------------
template<bool FINAL>
__global__ __launch_bounds__(256) void gru_kernel(
    const short* __restrict__ m, const short* __restrict__ h,
    const short* __restrict__ Wg, const float* __restrict__ bg,
    const float* __restrict__ g3, const float* __restrict__ b3,
    short* __restrict__ hout, void* __restrict__ xout)
{
    __shared__ __align__(16) char smem[64 * 520 * 2];   // Os (epilogue)
    short* As = (short*)smem;                           // 64x40
    short* Ws = (short*)(smem + 64 * 40 * 2);           // 512x40
    short* Os = (short*)smem;                           // 64x520

    const int tid  = threadIdx.x;
    const int lane = tid & 63, wid = tid >> 6;
    const int t16 = lane & 15, quad = lane >> 4;
    const long blockM = (long)blockIdx.x * 64;

    f32x4 acc[4][8];
    for (int i = 0; i < 4; i++)
        for (int j = 0; j < 8; j++)
            acc[i][j] = (f32x4){0.f, 0.f, 0.f, 0.f};

    for (int k0 = 0; k0 < 256; k0 += 32) {
        const short* src = (k0 < 128) ? m : h;
        {
            const int r = tid >> 2, c = (tid & 3) * 8;
            *(short8*)&As[r * 40 + c] =
                *(const short8*)(src + (blockM + r) * 128 + (k0 & 127) + c);
        }
        for (int g = 0; g < 8; g++) {
            const int idx = tid + g * 256;
            const int r = idx >> 2, c = (idx & 3) * 8;
            *(short8*)&Ws[r * 40 + c] = *(const short8*)(Wg + (long)r * 256 + k0 + c);
        }
        __syncthreads();
        short8 a[4];
        for (int mi = 0; mi < 4; mi++)
            a[mi] = *(const short8*)&As[(mi * 16 + t16) * 40 + quad * 8];
        for (int ni = 0; ni < 8; ni++) {
            short8 bf = *(const short8*)&Ws[(wid * 128 + ni * 16 + t16) * 40 + quad * 8];
            for (int mi = 0; mi < 4; mi++)
                acc[mi][ni] = __builtin_amdgcn_mfma_f32_16x16x32_bf16(a[mi], bf, acc[mi][ni], 0, 0, 0);
        }
        __syncthreads();
    }

    // pre-activations -> Os (bf16, stride 520)
    for (int mi = 0; mi < 4; mi++)
        for (int ni = 0; ni < 8; ni++) {
            const int col = wid * 128 + ni * 16 + t16;
            const float bb = bg[col];
            for (int r = 0; r < 4; r++) {
                const int row = mi * 16 + quad * 4 + r;
                Os[row * 520 + col] = f2bf(acc[mi][ni][r] + bb);
            }
        }
    __syncthreads();

    // epilogue: thread t -> row t>>2, cols (t&3)*32..+32
    {
        const int row = tid >> 2;
        const int c0 = (tid & 3) * 32;
        const long gr = blockM + row;
        float hp[32], hv[32];
        for (int j = 0; j < 4; j++) {
            short8 hpv = *(const short8*)(h + gr * 128 + c0 + j * 8);
            short8 orv = *(const short8*)&Os[row * 520 + c0 + j * 8];
            short8 ozv = *(const short8*)&Os[row * 520 + 128 + c0 + j * 8];
            short8 onv = *(const short8*)&Os[row * 520 + 256 + c0 + j * 8];
            short8 ohv = *(const short8*)&Os[row * 520 + 384 + c0 + j * 8];
            for (int q = 0; q < 8; q++) {
                float rr = 1.f / (1.f + __expf(-bf2f(orv[q])));
                float zz = 1.f / (1.f + __expf(-bf2f(ozv[q])));
                float nn = tanhf(bf2f(onv[q]) + rr * bf2f(ohv[q]));
                float hpq = bf2f(hpv[q]);
                hp[j * 8 + q] = hpq;
                hv[j * 8 + q] = (1.f - zz) * nn + zz * hpq;
            }
        }
        float s = 0.f;
        for (int j = 0; j < 32; j++) s += hv[j];
        s += __shfl_xor(s, 1); s += __shfl_xor(s, 2);
        float u = s * (1.0f / 128.0f);
        float vs = 0.f;
        for (int j = 0; j < 32; j++) { float d = hv[j] - u; vs += d * d; }
        vs += __shfl_xor(vs, 1); vs += __shfl_xor(vs, 2);
        float rstd = rsqrtf(vs * (1.0f / 128.0f) + 1e-12f);
        // store h'
        for (int j = 0; j < 4; j++) {
            short8 o;
            for (int q = 0; q < 8; q++) o[q] = f2bf(hv[j * 8 + q]);
            *(short8*)(hout + gr * 128 + c0 + j * 8) = o;
        }
        // store LN3(h')
        if (FINAL) {
            float* xo = (float*)xout;
            for (int j = 0; j < 8; j++) {
                float4 o;
                o.x = g3[c0 + j * 4 + 0] * (hv[j * 4 + 0] - u) * rstd + b3[c0 + j * 4 + 0];
                o.y = g3[c0 + j * 4 + 1] * (hv[j * 4 + 1] - u) * rstd + b3[c0 + j * 4 + 1];
                o.z = g3[c0 + j * 4 + 2] * (hv[j * 4 + 2] - u) * rstd + b3[c0 + j * 4 + 2];
                o.w = g3[c0 + j * 4 + 3] * (hv[j * 4 + 3] - u) * rstd + b3[c0 + j * 4 + 3];
                *(float4*)&xo[gr * 128 + c0 + j * 4] = o;
            }
        } else {
            short* xo = (short*)xout;
            for (int j = 0; j < 4; j++) {
                short8 o;
                for (int q = 0; q < 8; q++) {
                    const int c = c0 + j * 8 + q;
                    o[q] = f2bf(g3[c] * (hv[j * 8 + q] - u) * rstd + b3[c]);
                }
                *(short8*)(xo + gr * 128 + c0 + j * 8) = o;
            }
        }
    }
}

// ---------------------------------------------------------------------------
// CSR build
// ---------------------------------------------------------------------------
__global__ void count_kernel(const int* __restrict__ dst, int* __restrict__ cnt) {
    int e = blockIdx.x * 256 + threadIdx.x;
    if (e < N_EDGES) atomicAdd(&cnt[dst[e]], 1);
}

__global__ __launch_bounds__(1024) void scan_kernel(const int* __restrict__ cnt,
                                                    int* __restrict__ rowptr) {
    __shared__ int lds[1024];
    const int tid = threadIdx.x;
    const int CH = 40;
    const int base = tid * CH;
    int sum = 0;
    for (int j = 0; j < CH; j++) { int i = base + j; if (i < N_NODES) sum += cnt[i]; }
    lds[tid] = sum;
    __syncthreads();
    for (int off = 1; off < 1024; off <<= 1) {
        int v = (tid >= off) ? lds[tid - off] : 0;
        __syncthreads();
        lds[tid] += v;
        __syncthreads();
    }
    int run = lds[tid] - sum;
    for (int j = 0; j < CH; j++) {
        int i = base + j;
        if (i < N_NODES) { rowptr[i] = run; run += cnt[i]; }
    }
    if (tid == 1023) rowptr[N_NODES] = lds[1023];
}

__global__ void fill_kernel(const int* __restrict__ src, const int* __restrict__ dst,
                            const int* __restrict__ rowptr, int* __restrict__ wo,
                            int* __restrict__ eslot, int* __restrict__ srcp) {
    int e = blockIdx.x * 256 + threadIdx.x;
    if (e < N_EDGES) {
        int d = dst[e];
        int pos = atomicAdd(&wo[d], 1);
        int slot = rowptr[d] + pos;
        eslot[e] = slot;
        srcp[slot] = src[e];
    }
}

// ---------------------------------------------------------------------------
// Edge attention (unchanged from R2): one wave/node, 4 edges in flight.
// ---------------------------------------------------------------------------
__global__ __launch_bounds__(256) void edge_attn_kernel(
    const short* __restrict__ QKVb, const short* __restrict__ EKV,
    const int* __restrict__ rowptr, const int* __restrict__ srcp,
    short* __restrict__ outb)
{
    const int wid = threadIdx.x >> 6, lane = threadIdx.x & 63;
    const int n = blockIdx.x * 4 + wid;
    if (n >= N_NODES) return;
    const int g = lane >> 4, l16 = lane & 15;
    const float scale = 0.17677669529663687f;

    short8 qv = *(const short8*)&QKVb[(long)n * 384 + l16 * 8];
    float qf[8];
#pragma unroll
    for (int j = 0; j < 8; j++) qf[j] = bf2f(qv[j]);

    const int beg = rowptr[n], end = rowptr[n + 1];
    float acc[8] = {0.f, 0.f, 0.f, 0.f, 0.f, 0.f, 0.f, 0.f};
    float ssum = 0.f;

    for (int i0 = beg; i0 < end; i0 += 4) {
        const int i = i0 + g;
        const bool valid = i < end;
        const int ii = valid ? i : beg;
        const int s = srcp[ii];
        short8 kv = *(const short8*)&EKV[(long)ii * 256 + l16 * 8];
        short8 vv = *(const short8*)&EKV[(long)ii * 256 + 128 + l16 * 8];
        short8 xk = *(const short8*)&QKVb[(long)s * 384 + 128 + l16 * 8];
        short8 xv = *(const short8*)&QKVb[(long)s * 384 + 256 + l16 * 8];
        float dot = 0.f;
#pragma unroll
        for (int j = 0; j < 8; j++) dot += qf[j] * (bf2f(kv[j]) + bf2f(xk[j]));
        dot += __shfl_xor(dot, 1);
        dot += __shfl_xor(dot, 2);
        float e = valid ? __expf(dot * scale) : 0.f;
        ssum += e;
#pragma unroll
        for (int j = 0; j < 8; j++) acc[j] += e * (bf2f(vv[j]) + bf2f(xv[j]));
    }
#pragma unroll
    for (int j = 0; j < 8; j++) {
        acc[j] += __shfl_xor(acc[j], 16);
        acc[j] += __shfl_xor(acc[j], 32);
    }
    ssum += __shfl_xor(ssum, 16);
    ssum += __shfl_xor(ssum, 32);

    if (lane < 16) {
        float inv = 1.0f / (ssum + 1e-16f);
        short8 o;
#pragma unroll
        for (int j = 0; j < 8; j++) o[j] = f2bf(acc[j] * inv);
        *(short8*)&outb[(long)n * 128 + l16 * 8] = o;
    }
}

// ---------------------------------------------------------------------------
// Helpers
// ---------------------------------------------------------------------------
__global__ void cvt_kernel(const float* __restrict__ s, short* __restrict__ d, int n) {
    int i = (blockIdx.x * 256 + threadIdx.x) * 4;
    if (i < n) {
        float4 v = *(const float4*)(s + i);
        short4v sv;
        sv.x = f2bf(v.x); sv.y = f2bf(v.y); sv.z = f2bf(v.z); sv.w = f2bf(v.w);
        *(short4v*)(d + i) = sv;
    }
}
__global__ void bias_cat_kernel(const float* __restrict__ bq, const float* __restrict__ bk,
                                const float* __restrict__ bv, float* __restrict__ bqkv,
                                float* __restrict__ bkv) {
    int i = blockIdx.x * 256 + threadIdx.x;
    if (i < 384) bqkv[i] = (i < 128) ? bq[i] : 0.0f;
    if (i < 256) bkv[i] = (i < 128) ? bk[i] : bv[i - 128];
}
__global__ void build_wg_kernel(const float* __restrict__ wih, const float* __restrict__ whh,
                                const float* __restrict__ bih, const float* __restrict__ bhh,
                                short* __restrict__ Wg, float* __restrict__ bg) {
    int idx = blockIdx.x * 256 + threadIdx.x;
    if (idx < 512 * 256) {
        int r = idx >> 8, k = idx & 255;
        float v;
        if (r < 256)      v = (k < 128) ? wih[r * 128 + k] : whh[r * 128 + k - 128];
        else if (r < 384) v = (k < 128) ? wih[r * 128 + k] : 0.f;
        else              v = (k < 128) ? 0.f : whh[(r - 128) * 128 + k - 128];
        Wg[idx] = f2bf(v);
    }
    if (idx < 512) {
        float b;
        if (idx < 256)      b = bih[idx] + bhh[idx];
        else if (idx < 384) b = bih[idx];
        else                b = bhh[idx - 128];
        bg[idx] = b;
    }
}

// ---------------------------------------------------------------------------
extern "C" void kernel_launch(void* const* d_in, const int* in_sizes, int n_in,
                              void* d_out, int out_size, void* d_ws, size_t ws_size,
                              hipStream_t stream) {
    const float* x_in  = (const float*)d_in[0];
    const int*   eidx  = (const int*)d_in[1];
    const float* ea    = (const float*)d_in[2];
    const float* wq    = (const float*)d_in[3];
    const float* bq    = (const float*)d_in[4];
    const float* wk    = (const float*)d_in[5];
    const float* bk    = (const float*)d_in[6];
    const float* wv    = (const float*)d_in[7];
    const float* bv    = (const float*)d_in[8];
    const float* w_ao  = (const float*)d_in[9];
    const float* b_ao  = (const float*)d_in[10];
    const float* ln1_g = (const float*)d_in[11];
    const float* ln1_b = (const float*)d_in[12];
    const float* w_int = (const float*)d_in[13];
    const float* b_int = (const float*)d_in[14];
    const float* w_out = (const float*)d_in[15];
    const float* b_out = (const float*)d_in[16];
    const float* ln2_g = (const float*)d_in[17];
    const float* ln2_b = (const float*)d_in[18];
    const float* w_ih  = (const float*)d_in[19];
    const float* w_hh  = (const float*)d_in[20];
    const float* b_ih  = (const float*)d_in[21];
    const float* b_hh  = (const float*)d_in[22];
    const float* ln3_g = (const float*)d_in[23];
    const float* ln3_b = (const float*)d_in[24];
    const int* srcv = eidx;
    const int* dstv = eidx + N_EDGES;

    char* ws = (char*)d_ws;
    size_t off = 0;
    auto alloc = [&](size_t bytes) -> void* {
        void* p = ws + off;
        off += (bytes + 255) & ~(size_t)255;
        return p;
    };
    short* EKV  = (short*)alloc((size_t)N_EDGES * 256 * 2);
    short* Wcat = (short*)alloc(384 * 128 * 2);
    short* Wao  = (short*)alloc(128 * 128 * 2);
    short* Wint = (short*)alloc(512 * 128 * 2);
    short* Wout = (short*)alloc(128 * 512 * 2);
    short* Wg   = (short*)alloc(512 * 256 * 2);
    float* bqkv = (float*)alloc(384 * 4);
    float* bkv  = (float*)alloc(256 * 4);
    float* bg   = (float*)alloc(512 * 4);
    int* cnt    = (int*)alloc((size_t)N_NODES * 4);
    int* wo     = (int*)alloc((size_t)N_NODES * 4);
    int* rowptr = (int*)alloc((size_t)(N_NODES + 1) * 4);
    int* eslot  = (int*)alloc((size_t)N_EDGES * 4);
    int* srcp   = (int*)alloc((size_t)N_EDGES * 4);
    short* xb     = (short*)alloc((size_t)N_NODES * 128 * 2);
    short* QKVb   = (short*)alloc((size_t)N_NODES * 384 * 2);
    short* attraw = (short*)alloc((size_t)N_NODES * 128 * 2);
    short* att    = (short*)alloc((size_t)N_NODES * 128 * 2);
    short* mbuf   = (short*)alloc((size_t)N_NODES * 128 * 2);
    short* hbuf   = (short*)alloc((size_t)N_NODES * 128 * 2);
    short* xbuf   = (short*)alloc((size_t)N_NODES * 128 * 2);
    if (off > ws_size) return;

    // weight/bias prep
    cvt_kernel<<<16, 256, 0, stream>>>(wq, Wcat, 16384);
    cvt_kernel<<<16, 256, 0, stream>>>(wk, Wcat + 16384, 16384);
    cvt_kernel<<<16, 256, 0, stream>>>(wv, Wcat + 32768, 16384);
    cvt_kernel<<<16, 256, 0, stream>>>(w_ao, Wao, 16384);
    cvt_kernel<<<64, 256, 0, stream>>>(w_int, Wint, 65536);
    cvt_kernel<<<64, 256, 0, stream>>>(w_out, Wout, 65536);
    cvt_kernel<<<5000, 256, 0, stream>>>(x_in, xb, N_NODES * 128);
    bias_cat_kernel<<<2, 256, 0, stream>>>(bq, bk, bv, bqkv, bkv);
    build_wg_kernel<<<512, 256, 0, stream>>>(w_ih, w_hh, b_ih, b_hh, Wg, bg);

    // CSR by dst
    hipMemsetAsync(cnt, 0, (size_t)N_NODES * 4, stream);
    hipMemsetAsync(wo, 0, (size_t)N_NODES * 4, stream);
    count_kernel<<<1250, 256, 0, stream>>>(dstv, cnt);
    scan_kernel<<<1, 1024, 0, stream>>>(cnt, rowptr);
    fill_kernel<<<1250, 256, 0, stream>>>(srcv, dstv, rowptr, wo, eslot, srcp);

    // EKV (sequential read, scattered write into CSR order)
    ekv_kernel<<<5000, 256, 0, stream>>>(ea, Wcat + 128 * 128, bkv, eslot, EKV);

    const short* xcur = xb;
    const short* hcur = xb;
    for (int t = 0; t < T_ITERS; t++) {
        gemm_bf16<12, 0><<<dim3(625, 1), 256, 0, stream>>>(
            xcur, Wcat, bqkv, nullptr, QKVb, nullptr, nullptr, N_NODES, 128, 384);
        edge_attn_kernel<<<10000, 256, 0, stream>>>(QKVb, EKV, rowptr, srcp, attraw);
        gemm_bf16<4, 1><<<dim3(625, 1), 256, 0, stream>>>(
            attraw, Wao, b_ao, xcur, att, ln1_g, ln1_b, N_NODES, 128, 128);
        ffn_kernel<<<313, 256, 0, stream>>>(
            att, Wint, Wout, b_int, b_out, ln2_g, ln2_b, mbuf);
        if (t == T_ITERS - 1)
            gru_kernel<true><<<625, 256, 0, stream>>>(
                mbuf, hcur, Wg, bg, ln3_g, ln3_b, hbuf, d_out);
        else
            gru_kernel<false><<<625, 256, 0, stream>>>(
                mbuf, hcur, Wg, bg, ln3_g, ln3_b, hbuf, xbuf);
        xcur = xbuf;
        hcur = hbuf;
    }
}

// Round 4
// 1116.929 us; speedup vs baseline: 1.5946x; 1.2907x over previous
//
#include <hip/hip_runtime.h>
#include <hip/hip_bf16.h>
#include <math.h>

#define N_NODES 40000
#define N_EDGES 320000
#define T_ITERS 3

typedef __attribute__((ext_vector_type(8))) short short8;
typedef __attribute__((ext_vector_type(4))) short short4v;
typedef __attribute__((ext_vector_type(4))) float f32x4;

static __device__ __forceinline__ short f2bf(float f) {
    union { float f; unsigned u; } x; x.f = f;
    unsigned r = (x.u + 0x7fffu + ((x.u >> 16) & 1u)) >> 16;
    return (short)r;
}
static __device__ __forceinline__ float bf2f(short s) {
    union { unsigned u; float f; } x; x.u = ((unsigned)(unsigned short)s) << 16;
    return x.f;
}

// ---------------------------------------------------------------------------
// MFMA GEMM (bf16 A): C[M,NC] = A[M,K] @ W[NC,K]^T + bias. Tile 64 x 32*NI.
// Used for QKV: NI=4, grid (625, 3).
// ---------------------------------------------------------------------------
template<int NI>
__global__ __launch_bounds__(256) void gemm_bf16(
    const short* __restrict__ A, const short* __restrict__ W,
    const float* __restrict__ bias, short* __restrict__ Cb,
    int M, int K, int NC)
{
    constexpr int NT = 32 * NI;
    __shared__ __align__(16) short As[64 * 40];
    __shared__ __align__(16) short Ws[NT * 40];

    const int tid  = threadIdx.x;
    const int lane = tid & 63, wid = tid >> 6;
    const int wm = wid & 1, wn = wid >> 1;
    const int t16 = lane & 15, quad = lane >> 4;
    const long blockM = (long)blockIdx.x * 64;
    const int colBase = blockIdx.y * NT;

    f32x4 acc[2][NI];
    for (int i = 0; i < 2; i++)
        for (int j = 0; j < NI; j++)
            acc[i][j] = (f32x4){0.f, 0.f, 0.f, 0.f};

    for (int k0 = 0; k0 < K; k0 += 32) {
        {
            const int r = tid >> 2, c = (tid & 3) * 8;
            *(short8*)&As[r * 40 + c] = *(const short8*)(A + (blockM + r) * K + k0 + c);
        }
        for (int gg = 0; gg < NI / 2; gg++) {
            const int chunk = tid + gg * 256;
            const int r = chunk >> 2, c = (chunk & 3) * 8;
            *(short8*)&Ws[r * 40 + c] =
                *(const short8*)(W + (long)(colBase + r) * K + k0 + c);
        }
        __syncthreads();
        short8 a0 = *(const short8*)&As[(wm * 32 + t16) * 40 + quad * 8];
        short8 a1 = *(const short8*)&As[(wm * 32 + 16 + t16) * 40 + quad * 8];
        for (int ni = 0; ni < NI; ni++) {
            short8 bf = *(const short8*)&Ws[(wn * 16 * NI + ni * 16 + t16) * 40 + quad * 8];
            acc[0][ni] = __builtin_amdgcn_mfma_f32_16x16x32_bf16(a0, bf, acc[0][ni], 0, 0, 0);
            acc[1][ni] = __builtin_amdgcn_mfma_f32_16x16x32_bf16(a1, bf, acc[1][ni], 0, 0, 0);
        }
        __syncthreads();
    }

    for (int mi = 0; mi < 2; mi++)
        for (int ni = 0; ni < NI; ni++) {
            const int gc = colBase + wn * 16 * NI + ni * 16 + t16;
            for (int r = 0; r < 4; r++) {
                long gr = blockM + wm * 32 + mi * 16 + quad * 4 + r;
                float v = acc[mi][ni][r];
                if (bias) v += bias[gc];
                Cb[gr * (long)NC + gc] = f2bf(v);
            }
        }
}

// ---------------------------------------------------------------------------
// EKV GEMM: EKV[e] = ea[e] @ [wk;wv]^T + [bk;bv]  (bf16 [E,256], edge order)
// Sequential reads AND sequential writes. LDS transpose stride 276
// (4*276 shorts = 552 dwords == 8 mod 32 -> quads on banks {0,8,16,24}).
// ---------------------------------------------------------------------------
__global__ __launch_bounds__(256) void ekv_kernel(
    const float* __restrict__ ea, const short* __restrict__ Wkv,
    const float* __restrict__ bkv, short* __restrict__ EKV)
{
    __shared__ __align__(16) char smem[64 * 276 * 2];
    short* As = (short*)smem;                 // 64x40
    short* Ws = (short*)(smem + 64 * 40 * 2); // 256x40
    short* Cs = (short*)smem;                 // 64x276

    const int tid  = threadIdx.x;
    const int lane = tid & 63, wid = tid >> 6;
    const int t16 = lane & 15, quad = lane >> 4;
    const long blockM = (long)blockIdx.x * 64;

    f32x4 acc[4][4];
    for (int i = 0; i < 4; i++)
        for (int j = 0; j < 4; j++)
            acc[i][j] = (f32x4){0.f, 0.f, 0.f, 0.f};

    for (int k0 = 0; k0 < 128; k0 += 32) {
        for (int g = 0; g < 2; g++) {
            const int r = (tid >> 3) + g * 32, c = (tid & 7) * 4;
            const float4 v = *(const float4*)(ea + (blockM + r) * 128 + k0 + c);
            short4v sv;
            sv.x = f2bf(v.x); sv.y = f2bf(v.y); sv.z = f2bf(v.z); sv.w = f2bf(v.w);
            *(short4v*)&As[r * 40 + c] = sv;
        }
        for (int g = 0; g < 4; g++) {
            const int idx = tid + g * 256;
            const int r = idx >> 2, c = (idx & 3) * 8;
            *(short8*)&Ws[r * 40 + c] = *(const short8*)(Wkv + (long)r * 128 + k0 + c);
        }
        __syncthreads();
        short8 a[4];
        for (int mi = 0; mi < 4; mi++)
            a[mi] = *(const short8*)&As[(mi * 16 + t16) * 40 + quad * 8];
        for (int ni = 0; ni < 4; ni++) {
            short8 bf = *(const short8*)&Ws[(wid * 64 + ni * 16 + t16) * 40 + quad * 8];
            for (int mi = 0; mi < 4; mi++)
                acc[mi][ni] = __builtin_amdgcn_mfma_f32_16x16x32_bf16(a[mi], bf, acc[mi][ni], 0, 0, 0);
        }
        __syncthreads();
    }

    for (int mi = 0; mi < 4; mi++)
        for (int ni = 0; ni < 4; ni++) {
            const int col = wid * 64 + ni * 16 + t16;
            const float bv_ = bkv[col];
            for (int r = 0; r < 4; r++) {
                const int row = mi * 16 + quad * 4 + r;
                Cs[row * 276 + col] = f2bf(acc[mi][ni][r] + bv_);
            }
        }
    __syncthreads();
    for (int it = 0; it < 8; it++) {
        const int idx = it * 256 + tid;
        const int row = idx >> 5, c8 = idx & 31;
        *(short8*)(EKV + (blockM + row) * 256 + c8 * 8) = *(const short8*)&Cs[row * 276 + c8 * 8];
    }
}

// ---------------------------------------------------------------------------
// Fused attention block: att = LN1( attn_out @ Wao^T + b_ao + x ) is NOT here;
// this kernel is raw edge attention. One wave per node, 8 edges in flight
// (8 lanes/edge, 16 dims/lane). epair[slot] = {src, edge}.
// ---------------------------------------------------------------------------
__global__ __launch_bounds__(256) void edge_attn_kernel(
    const short* __restrict__ QKVb, const short* __restrict__ EKV,
    const int* __restrict__ rowptr, const int2* __restrict__ epair,
    short* __restrict__ outb)
{
    const int wid = threadIdx.x >> 6, lane = threadIdx.x & 63;
    const int n = blockIdx.x * 4 + wid;
    if (n >= N_NODES) return;
    const int g = lane >> 3, l8 = lane & 7;
    const int d0 = l8 * 16;
    const float scale = 0.17677669529663687f;  // 1/sqrt(32)

    short8 q0 = *(const short8*)&QKVb[(long)n * 384 + d0];
    short8 q1 = *(const short8*)&QKVb[(long)n * 384 + d0 + 8];
    float qf[16];
#pragma unroll
    for (int j = 0; j < 8; j++) { qf[j] = bf2f(q0[j]); qf[8 + j] = bf2f(q1[j]); }

    const int beg = rowptr[n], end = rowptr[n + 1];
    float acc[16];
#pragma unroll
    for (int j = 0; j < 16; j++) acc[j] = 0.f;
    float ssum = 0.f;

    for (int i0 = beg; i0 < end; i0 += 8) {
        const int i = i0 + g;
        const bool valid = i < end;
        const int ii = valid ? i : beg;
        const int2 pe = epair[ii];
        const long s = pe.x, e = pe.y;
        short8 k0 = *(const short8*)&EKV[e * 256 + d0];
        short8 k1 = *(const short8*)&EKV[e * 256 + d0 + 8];
        short8 xk0 = *(const short8*)&QKVb[s * 384 + 128 + d0];
        short8 xk1 = *(const short8*)&QKVb[s * 384 + 128 + d0 + 8];
        short8 v0 = *(const short8*)&EKV[e * 256 + 128 + d0];
        short8 v1 = *(const short8*)&EKV[e * 256 + 128 + d0 + 8];
        short8 xv0 = *(const short8*)&QKVb[s * 384 + 256 + d0];
        short8 xv1 = *(const short8*)&QKVb[s * 384 + 256 + d0 + 8];
        float dot = 0.f;
#pragma unroll
        for (int j = 0; j < 8; j++) {
            dot += qf[j] * (bf2f(k0[j]) + bf2f(xk0[j]));
            dot += qf[8 + j] * (bf2f(k1[j]) + bf2f(xk1[j]));
        }
        dot += __shfl_xor(dot, 1);   // head's other 16 dims
        float a = valid ? __expf(dot * scale) : 0.f;
        ssum += a;
#pragma unroll
        for (int j = 0; j < 8; j++) {
            acc[j]     += a * (bf2f(v0[j]) + bf2f(xv0[j]));
            acc[8 + j] += a * (bf2f(v1[j]) + bf2f(xv1[j]));
        }
    }
    // reduce over the 8 edge-groups (lane bits 3,4,5)
#pragma unroll
    for (int o = 8; o < 64; o <<= 1) {
#pragma unroll
        for (int j = 0; j < 16; j++) acc[j] += __shfl_xor(acc[j], o);
        ssum += __shfl_xor(ssum, o);
    }
    if (g == 0) {
        float inv = 1.0f / (ssum + 1e-16f);
        short8 o0, o1;
#pragma unroll
        for (int j = 0; j < 8; j++) { o0[j] = f2bf(acc[j] * inv); o1[j] = f2bf(acc[8 + j] * inv); }
        *(short8*)&outb[(long)n * 128 + d0] = o0;
        *(short8*)&outb[(long)n * 128 + d0 + 8] = o1;
    }
}

// ---------------------------------------------------------------------------
// Fused Wao+LN1+FFN: att = LN1(attraw@Wao^T + b_ao + x);
// m = LN2( gelu(att@Wint^T+b_int) @ Wout^T + b_out + att ).
// Block: 64 rows, 4 waves (wave = 16 rows x 128 cols).
// ---------------------------------------------------------------------------
__global__ __launch_bounds__(256) void ffn_kernel(
    const short* __restrict__ attraw, const short* __restrict__ x,
    const short* __restrict__ Wao, const short* __restrict__ Wint,
    const short* __restrict__ Wout, const float* __restrict__ b_ao,
    const float* __restrict__ b_int, const float* __restrict__ b_out,
    const float* __restrict__ ln1_g, const float* __restrict__ ln1_b,
    const float* __restrict__ ln2_g, const float* __restrict__ ln2_b,
    short* __restrict__ Mout)
{
    __shared__ __align__(16) short As[64 * 136];   // x -> att
    __shared__ __align__(16) short Is[64 * 136];   // attraw -> inter chunks
    __shared__ __align__(16) short Ws[128 * 40];

    const int tid  = threadIdx.x;
    const int lane = tid & 63, wid = tid >> 6;
    const int t16 = lane & 15, quad = lane >> 4;
    const long blockM = (long)blockIdx.x * 64;

    // stage x -> As, attraw -> Is
    {
        const int r = tid >> 2, c = (tid & 3) * 32;
        const long gr = blockM + r;
        for (int j = 0; j < 4; j++) {
            *(short8*)&As[r * 136 + c + j * 8] = *(const short8*)(x + gr * 128 + c + j * 8);
            *(short8*)&Is[r * 136 + c + j * 8] = *(const short8*)(attraw + gr * 128 + c + j * 8);
        }
    }
    __syncthreads();

    // phase 0: attraw @ Wao^T
    f32x4 acc0[8];
    for (int j = 0; j < 8; j++) acc0[j] = (f32x4){0.f, 0.f, 0.f, 0.f};
    for (int k0 = 0; k0 < 128; k0 += 32) {
        const int r = tid >> 1, c = (tid & 1) * 16;
        *(short8*)&Ws[r * 40 + c]     = *(const short8*)(Wao + (long)r * 128 + k0 + c);
        *(short8*)&Ws[r * 40 + c + 8] = *(const short8*)(Wao + (long)r * 128 + k0 + c + 8);
        __syncthreads();
        short8 a = *(const short8*)&Is[(wid * 16 + t16) * 136 + k0 + quad * 8];
        for (int ni = 0; ni < 8; ni++) {
            short8 bf = *(const short8*)&Ws[(ni * 16 + t16) * 40 + quad * 8];
            acc0[ni] = __builtin_amdgcn_mfma_f32_16x16x32_bf16(a, bf, acc0[ni], 0, 0, 0);
        }
        __syncthreads();
    }
    // epilogue 0: +b_ao +x, LN1, att -> As (1:1 thread ownership, no hazard)
    for (int r = 0; r < 4; r++) {
        const int row = wid * 16 + quad * 4 + r;
        float vals[8];
        float s = 0.f;
        for (int ni = 0; ni < 8; ni++) {
            const int col = ni * 16 + t16;
            float v = acc0[ni][r] + b_ao[col] + bf2f(As[row * 136 + col]);
            vals[ni] = v;
            s += v;
        }
        for (int o = 1; o < 16; o <<= 1) s += __shfl_xor(s, o);
        float u = s * (1.0f / 128.0f);
        float vs = 0.f;
        for (int ni = 0; ni < 8; ni++) { float d = vals[ni] - u; vals[ni] = d; vs += d * d; }
        for (int o = 1; o < 16; o <<= 1) vs += __shfl_xor(vs, o);
        float rstd = rsqrtf(vs * (1.0f / 128.0f) + 1e-12f);
        for (int ni = 0; ni < 8; ni++) {
            const int col = ni * 16 + t16;
            As[row * 136 + col] = f2bf(ln1_g[col] * vals[ni] * rstd + ln1_b[col]);
        }
    }
    __syncthreads();

    // FFN
    f32x4 acc2[8];
    for (int j = 0; j < 8; j++) acc2[j] = (f32x4){0.f, 0.f, 0.f, 0.f};
    for (int kc = 0; kc < 4; kc++) {
        f32x4 acc1[8];
        for (int j = 0; j < 8; j++) acc1[j] = (f32x4){0.f, 0.f, 0.f, 0.f};
        for (int k0 = 0; k0 < 128; k0 += 32) {
            const int r = tid >> 1, c = (tid & 1) * 16;
            *(short8*)&Ws[r * 40 + c] =
                *(const short8*)(Wint + (long)(kc * 128 + r) * 128 + k0 + c);
            *(short8*)&Ws[r * 40 + c + 8] =
                *(const short8*)(Wint + (long)(kc * 128 + r) * 128 + k0 + c + 8);
            __syncthreads();
            short8 a = *(const short8*)&As[(wid * 16 + t16) * 136 + k0 + quad * 8];
            for (int ni = 0; ni < 8; ni++) {
                short8 bf = *(const short8*)&Ws[(ni * 16 + t16) * 40 + quad * 8];
                acc1[ni] = __builtin_amdgcn_mfma_f32_16x16x32_bf16(a, bf, acc1[ni], 0, 0, 0);
            }
            __syncthreads();
        }
        for (int ni = 0; ni < 8; ni++) {
            const int col = ni * 16 + t16;
            const float bi = b_int[kc * 128 + col];
            for (int r = 0; r < 4; r++) {
                const int row = wid * 16 + quad * 4 + r;
                float v = acc1[ni][r] + bi;
                v = 0.5f * v * (1.0f + erff(v * 0.70710678118654752f));
                Is[row * 136 + col] = f2bf(v);
            }
        }
        __syncthreads();
        for (int k0 = 0; k0 < 128; k0 += 32) {
            const int r = tid >> 1, c = (tid & 1) * 16;
            *(short8*)&Ws[r * 40 + c] =
                *(const short8*)(Wout + (long)r * 512 + kc * 128 + k0 + c);
            *(short8*)&Ws[r * 40 + c + 8] =
                *(const short8*)(Wout + (long)r * 512 + kc * 128 + k0 + c + 8);
            __syncthreads();
            short8 a = *(const short8*)&Is[(wid * 16 + t16) * 136 + k0 + quad * 8];
            for (int ni = 0; ni < 8; ni++) {
                short8 bf = *(const short8*)&Ws[(ni * 16 + t16) * 40 + quad * 8];
                acc2[ni] = __builtin_amdgcn_mfma_f32_16x16x32_bf16(a, bf, acc2[ni], 0, 0, 0);
            }
            __syncthreads();
        }
    }

    // epilogue 2: +b_out + att, LN2, store
    for (int r = 0; r < 4; r++) {
        const int row = wid * 16 + quad * 4 + r;
        const long gr = blockM + row;
        float vals[8];
        float s = 0.f;
        for (int ni = 0; ni < 8; ni++) {
            const int col = ni * 16 + t16;
            float v = acc2[ni][r] + b_out[col] + bf2f(As[row * 136 + col]);
            vals[ni] = v;
            s += v;
        }
        for (int o = 1; o < 16; o <<= 1) s += __shfl_xor(s, o);
        float u = s * (1.0f / 128.0f);
        float vs = 0.f;
        for (int ni = 0; ni < 8; ni++) { float d = vals[ni] - u; vals[ni] = d; vs += d * d; }
        for (int o = 1; o < 16; o <<= 1) vs += __shfl_xor(vs, o);
        float rstd = rsqrtf(vs * (1.0f / 128.0f) + 1e-12f);
        for (int ni = 0; ni < 8; ni++) {
            const int col = ni * 16 + t16;
            Mout[gr * 128 + col] = f2bf(ln2_g[col] * vals[ni] * rstd + ln2_b[col]);
        }
    }
}

// ---------------------------------------------------------------------------
// Fused GRU: [m|h](N,256) @ Wg(512,256)^T -> {ir+hr, iz+hz, in, hn}
// + gates + h' + LN3.  Block 64 rows; wave w -> cols w*128.
// ---------------------------------------------------------------------------
template<bool FINAL>
__global__ __launch_bounds__(256) void gru_kernel(
    const short* __restrict__ m, const short* __restrict__ h,
    const short* __restrict__ Wg, const float* __restrict__ bg,
    const float* __restrict__ g3, const float* __restrict__ b3,
    short* __restrict__ hout, void* __restrict__ xout)
{
    __shared__ __align__(16) char smem[64 * 520 * 2];
    short* As = (short*)smem;
    short* Ws = (short*)(smem + 64 * 40 * 2);
    short* Os = (short*)smem;

    const int tid  = threadIdx.x;
    const int lane = tid & 63, wid = tid >> 6;
    const int t16 = lane & 15, quad = lane >> 4;
    const long blockM = (long)blockIdx.x * 64;

    f32x4 acc[4][8];
    for (int i = 0; i < 4; i++)
        for (int j = 0; j < 8; j++)
            acc[i][j] = (f32x4){0.f, 0.f, 0.f, 0.f};

    for (int k0 = 0; k0 < 256; k0 += 32) {
        const short* src = (k0 < 128) ? m : h;
        {
            const int r = tid >> 2, c = (tid & 3) * 8;
            *(short8*)&As[r * 40 + c] =
                *(const short8*)(src + (blockM + r) * 128 + (k0 & 127) + c);
        }
        for (int g = 0; g < 8; g++) {
            const int idx = tid + g * 256;
            const int r = idx >> 2, c = (idx & 3) * 8;
            *(short8*)&Ws[r * 40 + c] = *(const short8*)(Wg + (long)r * 256 + k0 + c);
        }
        __syncthreads();
        short8 a[4];
        for (int mi = 0; mi < 4; mi++)
            a[mi] = *(const short8*)&As[(mi * 16 + t16) * 40 + quad * 8];
        for (int ni = 0; ni < 8; ni++) {
            short8 bf = *(const short8*)&Ws[(wid * 128 + ni * 16 + t16) * 40 + quad * 8];
            for (int mi = 0; mi < 4; mi++)
                acc[mi][ni] = __builtin_amdgcn_mfma_f32_16x16x32_bf16(a[mi], bf, acc[mi][ni], 0, 0, 0);
        }
        __syncthreads();
    }

    for (int mi = 0; mi < 4; mi++)
        for (int ni = 0; ni < 8; ni++) {
            const int col = wid * 128 + ni * 16 + t16;
            const float bb = bg[col];
            for (int r = 0; r < 4; r++) {
                const int row = mi * 16 + quad * 4 + r;
                Os[row * 520 + col] = f2bf(acc[mi][ni][r] + bb);
            }
        }
    __syncthreads();

    {
        const int row = tid >> 2;
        const int c0 = (tid & 3) * 32;
        const long gr = blockM + row;
        float hv[32];
        for (int j = 0; j < 4; j++) {
            short8 hpv = *(const short8*)(h + gr * 128 + c0 + j * 8);
            short8 orv = *(const short8*)&Os[row * 520 + c0 + j * 8];
            short8 ozv = *(const short8*)&Os[row * 520 + 128 + c0 + j * 8];
            short8 onv = *(const short8*)&Os[row * 520 + 256 + c0 + j * 8];
            short8 ohv = *(const short8*)&Os[row * 520 + 384 + c0 + j * 8];
            for (int q = 0; q < 8; q++) {
                float rr = 1.f / (1.f + __expf(-bf2f(orv[q])));
                float zz = 1.f / (1.f + __expf(-bf2f(ozv[q])));
                float nn = tanhf(bf2f(onv[q]) + rr * bf2f(ohv[q]));
                float hpq = bf2f(hpv[q]);
                hv[j * 8 + q] = (1.f - zz) * nn + zz * hpq;
            }
        }
        float s = 0.f;
        for (int j = 0; j < 32; j++) s += hv[j];
        s += __shfl_xor(s, 1); s += __shfl_xor(s, 2);
        float u = s * (1.0f / 128.0f);
        float vs = 0.f;
        for (int j = 0; j < 32; j++) { float d = hv[j] - u; vs += d * d; }
        vs += __shfl_xor(vs, 1); vs += __shfl_xor(vs, 2);
        float rstd = rsqrtf(vs * (1.0f / 128.0f) + 1e-12f);
        for (int j = 0; j < 4; j++) {
            short8 o;
            for (int q = 0; q < 8; q++) o[q] = f2bf(hv[j * 8 + q]);
            *(short8*)(hout + gr * 128 + c0 + j * 8) = o;
        }
        if (FINAL) {
            float* xo = (float*)xout;
            for (int j = 0; j < 8; j++) {
                float4 o;
                o.x = g3[c0 + j * 4 + 0] * (hv[j * 4 + 0] - u) * rstd + b3[c0 + j * 4 + 0];
                o.y = g3[c0 + j * 4 + 1] * (hv[j * 4 + 1] - u) * rstd + b3[c0 + j * 4 + 1];
                o.z = g3[c0 + j * 4 + 2] * (hv[j * 4 + 2] - u) * rstd + b3[c0 + j * 4 + 2];
                o.w = g3[c0 + j * 4 + 3] * (hv[j * 4 + 3] - u) * rstd + b3[c0 + j * 4 + 3];
                *(float4*)&xo[gr * 128 + c0 + j * 4] = o;
            }
        } else {
            short* xo = (short*)xout;
            for (int j = 0; j < 4; j++) {
                short8 o;
                for (int q = 0; q < 8; q++) {
                    const int c = c0 + j * 8 + q;
                    o[q] = f2bf(g3[c] * (hv[j * 8 + q] - u) * rstd + b3[c]);
                }
                *(short8*)(xo + gr * 128 + c0 + j * 8) = o;
            }
        }
    }
}

// ---------------------------------------------------------------------------
// CSR build
// ---------------------------------------------------------------------------
__global__ void count_kernel(const int* __restrict__ dst, int* __restrict__ cnt) {
    int e = blockIdx.x * 256 + threadIdx.x;
    if (e < N_EDGES) atomicAdd(&cnt[dst[e]], 1);
}

__global__ __launch_bounds__(1024) void scan_kernel(const int* __restrict__ cnt,
                                                    int* __restrict__ rowptr) {
    __shared__ int lds[1024];
    const int tid = threadIdx.x;
    const int CH = 40;
    const int base = tid * CH;
    int sum = 0;
    for (int j = 0; j < CH; j++) { int i = base + j; if (i < N_NODES) sum += cnt[i]; }
    lds[tid] = sum;
    __syncthreads();
    for (int off = 1; off < 1024; off <<= 1) {
        int v = (tid >= off) ? lds[tid - off] : 0;
        __syncthreads();
        lds[tid] += v;
        __syncthreads();
    }
    int run = lds[tid] - sum;
    for (int j = 0; j < CH; j++) {
        int i = base + j;
        if (i < N_NODES) { rowptr[i] = run; run += cnt[i]; }
    }
    if (tid == 1023) rowptr[N_NODES] = lds[1023];
}

__global__ void fill_kernel(const int* __restrict__ src, const int* __restrict__ dst,
                            const int* __restrict__ rowptr, int* __restrict__ wo,
                            int2* __restrict__ epair) {
    int e = blockIdx.x * 256 + threadIdx.x;
    if (e < N_EDGES) {
        int d = dst[e];
        int pos = atomicAdd(&wo[d], 1);
        int slot = rowptr[d] + pos;
        epair[slot] = make_int2(src[e], e);
    }
}

// ---------------------------------------------------------------------------
// Helpers
// ---------------------------------------------------------------------------
__global__ void cvt_kernel(const float* __restrict__ s, short* __restrict__ d, int n) {
    int i = (blockIdx.x * 256 + threadIdx.x) * 4;
    if (i < n) {
        float4 v = *(const float4*)(s + i);
        short4v sv;
        sv.x = f2bf(v.x); sv.y = f2bf(v.y); sv.z = f2bf(v.z); sv.w = f2bf(v.w);
        *(short4v*)(d + i) = sv;
    }
}
__global__ void bias_cat_kernel(const float* __restrict__ bq, const float* __restrict__ bk,
                                const float* __restrict__ bv, float* __restrict__ bqkv,
                                float* __restrict__ bkv) {
    int i = blockIdx.x * 256 + threadIdx.x;
    if (i < 384) bqkv[i] = (i < 128) ? bq[i] : 0.0f;
    if (i < 256) bkv[i] = (i < 128) ? bk[i] : bv[i - 128];
}
__global__ void build_wg_kernel(const float* __restrict__ wih, const float* __restrict__ whh,
                                const float* __restrict__ bih, const float* __restrict__ bhh,
                                short* __restrict__ Wg, float* __restrict__ bg) {
    int idx = blockIdx.x * 256 + threadIdx.x;
    if (idx < 512 * 256) {
        int r = idx >> 8, k = idx & 255;
        float v;
        if (r < 256)      v = (k < 128) ? wih[r * 128 + k] : whh[r * 128 + k - 128];
        else if (r < 384) v = (k < 128) ? wih[r * 128 + k] : 0.f;
        else              v = (k < 128) ? 0.f : whh[(r - 128) * 128 + k - 128];
        Wg[idx] = f2bf(v);
    }
    if (idx < 512) {
        float b;
        if (idx < 256)      b = bih[idx] + bhh[idx];
        else if (idx < 384) b = bih[idx];
        else                b = bhh[idx - 128];
        bg[idx] = b;
    }
}

// ---------------------------------------------------------------------------
extern "C" void kernel_launch(void* const* d_in, const int* in_sizes, int n_in,
                              void* d_out, int out_size, void* d_ws, size_t ws_size,
                              hipStream_t stream) {
    const float* x_in  = (const float*)d_in[0];
    const int*   eidx  = (const int*)d_in[1];
    const float* ea    = (const float*)d_in[2];
    const float* wq    = (const float*)d_in[3];
    const float* bq    = (const float*)d_in[4];
    const float* wk    = (const float*)d_in[5];
    const float* bk    = (const float*)d_in[6];
    const float* wv    = (const float*)d_in[7];
    const float* bv    = (const float*)d_in[8];
    const float* w_ao  = (const float*)d_in[9];
    const float* b_ao  = (const float*)d_in[10];
    const float* ln1_g = (const float*)d_in[11];
    const float* ln1_b = (const float*)d_in[12];
    const float* w_int = (const float*)d_in[13];
    const float* b_int = (const float*)d_in[14];
    const float* w_out = (const float*)d_in[15];
    const float* b_out = (const float*)d_in[16];
    const float* ln2_g = (const float*)d_in[17];
    const float* ln2_b = (const float*)d_in[18];
    const float* w_ih  = (const float*)d_in[19];
    const float* w_hh  = (const float*)d_in[20];
    const float* b_ih  = (const float*)d_in[21];
    const float* b_hh  = (const float*)d_in[22];
    const float* ln3_g = (const float*)d_in[23];
    const float* ln3_b = (const float*)d_in[24];
    const int* srcv = eidx;
    const int* dstv = eidx + N_EDGES;

    char* ws = (char*)d_ws;
    size_t off = 0;
    auto alloc = [&](size_t bytes) -> void* {
        void* p = ws + off;
        off += (bytes + 255) & ~(size_t)255;
        return p;
    };
    short* EKV  = (short*)alloc((size_t)N_EDGES * 256 * 2);
    short* Wcat = (short*)alloc(384 * 128 * 2);
    short* Wao  = (short*)alloc(128 * 128 * 2);
    short* Wint = (short*)alloc(512 * 128 * 2);
    short* Wout = (short*)alloc(128 * 512 * 2);
    short* Wg   = (short*)alloc(512 * 256 * 2);
    float* bqkv = (float*)alloc(384 * 4);
    float* bkv  = (float*)alloc(256 * 4);
    float* bg   = (float*)alloc(512 * 4);
    int* cnt    = (int*)alloc((size_t)N_NODES * 4);
    int* wo     = (int*)alloc((size_t)N_NODES * 4);
    int* rowptr = (int*)alloc((size_t)(N_NODES + 1) * 4);
    int2* epair = (int2*)alloc((size_t)N_EDGES * 8);
    short* xb     = (short*)alloc((size_t)N_NODES * 128 * 2);
    short* QKVb   = (short*)alloc((size_t)N_NODES * 384 * 2);
    short* attraw = (short*)alloc((size_t)N_NODES * 128 * 2);
    short* mbuf   = (short*)alloc((size_t)N_NODES * 128 * 2);
    short* hbuf   = (short*)alloc((size_t)N_NODES * 128 * 2);
    short* xbuf   = (short*)alloc((size_t)N_NODES * 128 * 2);
    if (off > ws_size) return;

    cvt_kernel<<<16, 256, 0, stream>>>(wq, Wcat, 16384);
    cvt_kernel<<<16, 256, 0, stream>>>(wk, Wcat + 16384, 16384);
    cvt_kernel<<<16, 256, 0, stream>>>(wv, Wcat + 32768, 16384);
    cvt_kernel<<<16, 256, 0, stream>>>(w_ao, Wao, 16384);
    cvt_kernel<<<64, 256, 0, stream>>>(w_int, Wint, 65536);
    cvt_kernel<<<64, 256, 0, stream>>>(w_out, Wout, 65536);
    cvt_kernel<<<5000, 256, 0, stream>>>(x_in, xb, N_NODES * 128);
    bias_cat_kernel<<<2, 256, 0, stream>>>(bq, bk, bv, bqkv, bkv);
    build_wg_kernel<<<512, 256, 0, stream>>>(w_ih, w_hh, b_ih, b_hh, Wg, bg);

    hipMemsetAsync(cnt, 0, (size_t)N_NODES * 4, stream);
    hipMemsetAsync(wo, 0, (size_t)N_NODES * 4, stream);
    count_kernel<<<1250, 256, 0, stream>>>(dstv, cnt);
    scan_kernel<<<1, 1024, 0, stream>>>(cnt, rowptr);
    fill_kernel<<<1250, 256, 0, stream>>>(srcv, dstv, rowptr, wo, epair);

    ekv_kernel<<<5000, 256, 0, stream>>>(ea, Wcat + 128 * 128, bkv, EKV);

    const short* xcur = xb;
    const short* hcur = xb;
    for (int t = 0; t < T_ITERS; t++) {
        gemm_bf16<4><<<dim3(625, 3), 256, 0, stream>>>(
            xcur, Wcat, bqkv, QKVb, N_NODES, 128, 384);
        edge_attn_kernel<<<10000, 256, 0, stream>>>(QKVb, EKV, rowptr, epair, attraw);
        ffn_kernel<<<625, 256, 0, stream>>>(
            attraw, xcur, Wao, Wint, Wout, b_ao, b_int, b_out,
            ln1_g, ln1_b, ln2_g, ln2_b, mbuf);
        if (t == T_ITERS - 1)
            gru_kernel<true><<<625, 256, 0, stream>>>(
                mbuf, hcur, Wg, bg, ln3_g, ln3_b, hbuf, d_out);
        else
            gru_kernel<false><<<625, 256, 0, stream>>>(
                mbuf, hcur, Wg, bg, ln3_g, ln3_b, hbuf, xbuf);
        xcur = xbuf;
        hcur = hbuf;
    }
}